// Round 2
// baseline (435.506 us; speedup 1.0000x reference)
//
#include <hip/hip_runtime.h>
#include <hip/hip_bf16.h>
#include <stdint.h>

#define N_PTS 16384
#define C_CH  64
#define D_REF 5
#define LOG2E 1.44269504088896340736f
#define JSPLIT 16

typedef __attribute__((ext_vector_type(8))) short bf16x8;
typedef __attribute__((ext_vector_type(4))) float f32x4;

__device__ __forceinline__ unsigned short bf16rn(float v) {
    unsigned u = __builtin_bit_cast(unsigned, v) + 0x8000u;   // round-half-up
    return (unsigned short)(u >> 16);
}
__device__ __forceinline__ float bf16tof(unsigned short h) {
    unsigned u = ((unsigned)h) << 16;
    return __builtin_bit_cast(float, u);
}
__device__ __forceinline__ unsigned pack2bf16(float lo, float hi) {
    unsigned a = __builtin_bit_cast(unsigned, lo) + 0x8000u;
    unsigned b = __builtin_bit_cast(unsigned, hi) + 0x8000u;
    return __builtin_amdgcn_perm(b, a, 0x07060302u);
}
__device__ __forceinline__ float fast_exp2(float x) {
#if __has_builtin(__builtin_amdgcn_exp2f)
    return __builtin_amdgcn_exp2f(x);
#else
    return exp2f(x);
#endif
}

// ---------------------------------------------------------------------------
// prep 1: pack ref into G-MFMA fragment buffers.
//   packA[jtile16][lane][8] (A side, j): slots [rJh(0:5), rJh(5:10), rJl(10:15),
//                                               hjh(15), hjl(16), 1(17), 1(18), 0...]
//   packB[itile16][lane][8] (B side, i): slots [sIh, sIl, sIh, 1(15), 1(16),
//                                               hih(17), hil(18), 0...]
//   where sI = log2e*ri,  h = -0.5*log2e*|r|^2, hi/lo bf16 two-term splits.
//   => G = sum_k A_k B_k = log2e*(ri.rj) + hi + hj  (fp32-accurate to ~1e-3)
__global__ __launch_bounds__(256) void prep_pack_ref(
    const float* __restrict__ ref,
    unsigned short* __restrict__ packA,
    unsigned short* __restrict__ packB)
{
    const int gid  = blockIdx.x * 256 + threadIdx.x;   // 131072 total
    const int half = gid >> 16;                        // 0 = A(j), 1 = B(i)
    const int id   = gid & 0xFFFF;
    const int tile = id >> 6;
    const int lane = id & 63;
    const int q    = lane >> 4;
    const int m    = lane & 15;
    const int p    = tile * 16 + m;

    const float* r = ref + (size_t)p * D_REF;
    float rv[5];
    float sq = 0.f;
#pragma unroll
    for (int d = 0; d < 5; ++d) { rv[d] = r[d]; sq += rv[d] * rv[d]; }
    const float h = -0.5f * LOG2E * sq;

    unsigned short bh[5], bl[5];
#pragma unroll
    for (int d = 0; d < 5; ++d) {
        const float base = half ? rv[d] * LOG2E : rv[d];
        bh[d] = bf16rn(base);
        bl[d] = bf16rn(base - bf16tof(bh[d]));
    }
    const unsigned short hh  = bf16rn(h);
    const unsigned short hl  = bf16rn(h - bf16tof(hh));
    const unsigned short one = 0x3F80;

    unsigned short outv[8];
#pragma unroll
    for (int t = 0; t < 8; ++t) {
        const int k = q * 8 + t;
        unsigned short v = 0;
        if (!half) {
            if      (k < 5)   v = bh[k];
            else if (k < 10)  v = bh[k - 5];
            else if (k < 15)  v = bl[k - 10];
            else if (k == 15) v = hh;
            else if (k == 16) v = hl;
            else if (k <= 18) v = one;
        } else {
            if      (k < 5)   v = bh[k];
            else if (k < 10)  v = bl[k - 5];
            else if (k < 15)  v = bh[k - 10];
            else if (k <= 16) v = one;
            else if (k == 17) v = hh;
            else if (k == 18) v = hl;
        }
        outv[t] = v;
    }
    unsigned short* dst = (half ? packB : packA) + ((size_t)tile * 64 + lane) * 8;
    *(uint4*)dst = *(uint4*)outv;
}

// ---------------------------------------------------------------------------
// prep 2: pack U into PV A-fragments (bf16).
//   utPack[jtile32][ctile][lane][8]:  lane (q=lane>>4,m=lane&15) holds
//   Ut[c = ctile*16+m][j = jtile*32 + q*8 + t], t=0..7.
__global__ __launch_bounds__(256) void prep_pack_ut(
    const float* __restrict__ U, unsigned short* __restrict__ utPack)
{
    __shared__ unsigned short tile[64 * 80];          // [c][jloc], stride 80
    const int t  = threadIdx.x;
    const int j0 = blockIdx.x * 64;
    const int c  = t & 63;
    const int jb = t >> 6;
#pragma unroll
    for (int k = 0; k < 16; ++k) {
        const int jr = jb + k * 4;
        tile[c * 80 + jr] = bf16rn(U[(size_t)(j0 + jr) * C_CH + c]);  // coalesced by c
    }
    __syncthreads();
#pragma unroll
    for (int rep = 0; rep < 2; ++rep) {
        const int id   = rep * 256 + t;               // 512 frag-lanes
        const int lane = id & 63;
        const int ct   = (id >> 6) & 3;
        const int kt   = id >> 8;                     // 0..1
        const int m    = lane & 15;
        const int q    = lane >> 4;
        const int cc   = ct * 16 + m;
        const int jloc = kt * 32 + q * 8;
        const uint4 frag = *(const uint4*)&tile[cc * 80 + jloc];
        const int jtile  = blockIdx.x * 2 + kt;
        *(uint4*)&utPack[(((size_t)jtile * 4 + ct) * 64 + lane) * 8] = frag;
    }
}

// ---------------------------------------------------------------------------
// main: G-MFMA scores -> exp2 -> per-wave LDS round-trip -> PV-MFMA.
// grid 1024 = 64 i-blocks x 16 j-splits; block 256 = 4 waves.
// wave owns 4 i-tiles (64 i); block j-range = 1024 j = 8 chunks of 128.
__global__ __launch_bounds__(256, 3) void lsh_main(
    const float* __restrict__ U,
    const unsigned short* __restrict__ packA,
    const unsigned short* __restrict__ packB,
    const unsigned short* __restrict__ utPack,
    float* __restrict__ out)
{
    __shared__ __align__(16) unsigned short utLds[16 * 512];  // 16 KB, frag-linear
    __shared__ __align__(16) unsigned short sLds[4 * 512];    // 1 KB per wave

    const int t    = threadIdx.x;
    const int lane = t & 63;
    const int wave = t >> 6;
    const int q    = lane >> 4;
    const int m    = lane & 15;

    const int ib = blockIdx.x >> 4;
    const int js = blockIdx.x & 15;

    bf16x8 bfrag[4];
#pragma unroll
    for (int s = 0; s < 4; ++s) {
        const int itile = ib * 16 + wave * 4 + s;
        bfrag[s] = *(const bf16x8*)(packB + ((size_t)itile * 64 + lane) * 8);
    }

    f32x4 acc[4][4];
#pragma unroll
    for (int s = 0; s < 4; ++s)
#pragma unroll
        for (int ct = 0; ct < 4; ++ct) acc[s][ct] = (f32x4){0.f, 0.f, 0.f, 0.f};

    unsigned short* sBuf = sLds + wave * 512;
    // writer elem offset: S tile is stored so reader lane L' gets bytes [L'*16,+16)
    const int sWr0 = (q >> 1) * 128 + m * 8 + (q & 1) * 4;

    for (int chunk = 0; chunk < 8; ++chunk) {
        __syncthreads();
        {   // stage 16 KB of utPack (4 jtiles32 x 4 ctiles), linear copy
            const unsigned short* src = utPack + (size_t)(js * 32 + chunk * 4) * 2048;
#pragma unroll
            for (int r2 = 0; r2 < 4; ++r2)
                *(uint4*)&utLds[(r2 * 256 + t) * 8] =
                    *(const uint4*)(src + (size_t)(r2 * 256 + t) * 8);
        }
        __syncthreads();

#pragma unroll
        for (int kt = 0; kt < 4; ++kt) {
            const int jt0 = js * 64 + chunk * 8 + kt * 2;
            const bf16x8 ga0 = *(const bf16x8*)(packA + ((size_t)jt0 * 64 + lane) * 8);
            const bf16x8 ga1 = *(const bf16x8*)(packA + ((size_t)(jt0 + 1) * 64 + lane) * 8);
            bf16x8 uf[4];
#pragma unroll
            for (int ct = 0; ct < 4; ++ct)
                uf[ct] = *(const bf16x8*)&utLds[(kt * 4 + ct) * 512 + lane * 8];

#pragma unroll
            for (int s = 0; s < 4; ++s) {
                const f32x4 z = (f32x4){0.f, 0.f, 0.f, 0.f};
                f32x4 g0 = __builtin_amdgcn_mfma_f32_16x16x32_bf16(ga0, bfrag[s], z, 0, 0, 0);
                f32x4 g1 = __builtin_amdgcn_mfma_f32_16x16x32_bf16(ga1, bfrag[s], z, 0, 0, 0);
                float e0[4], e1[4];
#pragma unroll
                for (int r2 = 0; r2 < 4; ++r2) {
                    e0[r2] = fast_exp2(g0[r2]);
                    e1[r2] = fast_exp2(g1[r2]);
                }
                uint2 w0 = { pack2bf16(e0[0], e0[1]), pack2bf16(e0[2], e0[3]) };
                uint2 w1 = { pack2bf16(e1[0], e1[1]), pack2bf16(e1[2], e1[3]) };
                *(uint2*)&sBuf[sWr0]       = w0;   // g=0 rows (j 0..15)
                *(uint2*)&sBuf[sWr0 + 256] = w1;   // g=1 rows (j 16..31)
                // same-wave DS is in-order; read back as lane-sequential B-frag
                const bf16x8 sf = *(const bf16x8*)&sBuf[lane * 8];
#pragma unroll
                for (int ct = 0; ct < 4; ++ct)
                    acc[s][ct] = __builtin_amdgcn_mfma_f32_16x16x32_bf16(
                        uf[ct], sf, acc[s][ct], 0, 0, 0);
            }
        }
    }

#pragma unroll
    for (int s = 0; s < 4; ++s) {
        const int i_glob = (ib * 16 + wave * 4 + s) * 16 + m;
#pragma unroll
        for (int ct = 0; ct < 4; ++ct)
#pragma unroll
            for (int r2 = 0; r2 < 4; ++r2) {
                const int c = ct * 16 + q * 4 + r2;
                float val = acc[s][ct][r2];
                if (js == 0) val -= U[(size_t)i_glob * C_CH + c];
                atomicAdd(&out[(size_t)i_glob * C_CH + c], val);
            }
    }
}

extern "C" void kernel_launch(void* const* d_in, const int* in_sizes, int n_in,
                              void* d_out, int out_size, void* d_ws, size_t ws_size,
                              hipStream_t stream) {
    const float* U   = (const float*)d_in[0];
    const float* ref = (const float*)d_in[1];
    float* out = (float*)d_out;

    // ws: utPack 2 MB | packA 1 MB | packB 1 MB
    unsigned short* utPack = (unsigned short*)d_ws;
    unsigned short* packA  = (unsigned short*)((char*)d_ws + (size_t)2 * 1024 * 1024);
    unsigned short* packB  = (unsigned short*)((char*)d_ws + (size_t)3 * 1024 * 1024);

    hipMemsetAsync(d_out, 0, (size_t)out_size * sizeof(float), stream);
    prep_pack_ref<<<512, 256, 0, stream>>>(ref, packA, packB);
    prep_pack_ut<<<N_PTS / 64, 256, 0, stream>>>(U, utPack);
    lsh_main<<<64 * JSPLIT, 256, 0, stream>>>(U, packA, packB, utPack, out);
}

// Round 3
// 153.817 us; speedup vs baseline: 2.8313x; 2.8313x over previous
//
#include <hip/hip_runtime.h>
#include <hip/hip_bf16.h>
#include <stdint.h>

#define N_PTS 16384
#define C_CH  64
#define D_REF 5
#define LOG2E 1.44269504088896340736f
#define JSPLIT 8          // j-splits; partials reduced by second kernel
#define IBLOCKS 64        // 16384 / 256 i per block
#define CHUNKS 16         // (16384/JSPLIT)/128 j-chunks per block

typedef __attribute__((ext_vector_type(8))) short bf16x8;
typedef __attribute__((ext_vector_type(4))) float f32x4;

__device__ __forceinline__ unsigned short bf16rn(float v) {
    unsigned u = __builtin_bit_cast(unsigned, v) + 0x8000u;   // round-half-up
    return (unsigned short)(u >> 16);
}
__device__ __forceinline__ float bf16tof(unsigned short h) {
    unsigned u = ((unsigned)h) << 16;
    return __builtin_bit_cast(float, u);
}
__device__ __forceinline__ unsigned pack2bf16(float lo, float hi) {
    unsigned a = __builtin_bit_cast(unsigned, lo) + 0x8000u;
    unsigned b = __builtin_bit_cast(unsigned, hi) + 0x8000u;
    return __builtin_amdgcn_perm(b, a, 0x07060302u);
}
__device__ __forceinline__ float fast_exp2(float x) {
#if __has_builtin(__builtin_amdgcn_exp2f)
    return __builtin_amdgcn_exp2f(x);
#else
    return exp2f(x);
#endif
}

// ---------------------------------------------------------------------------
// prep 1: pack ref into G-MFMA fragment buffers (verified correct in R2).
//   G = sum_k A_k B_k = log2e*(ri.rj) + hi + hj  via hi/lo bf16 splits.
__global__ __launch_bounds__(256) void prep_pack_ref(
    const float* __restrict__ ref,
    unsigned short* __restrict__ packA,
    unsigned short* __restrict__ packB)
{
    const int gid  = blockIdx.x * 256 + threadIdx.x;   // 131072 total
    const int half = gid >> 16;                        // 0 = A(j), 1 = B(i)
    const int id   = gid & 0xFFFF;
    const int tile = id >> 6;
    const int lane = id & 63;
    const int q    = lane >> 4;
    const int m    = lane & 15;
    const int p    = tile * 16 + m;

    const float* r = ref + (size_t)p * D_REF;
    float rv[5];
    float sq = 0.f;
#pragma unroll
    for (int d = 0; d < 5; ++d) { rv[d] = r[d]; sq += rv[d] * rv[d]; }
    const float h = -0.5f * LOG2E * sq;

    unsigned short bh[5], bl[5];
#pragma unroll
    for (int d = 0; d < 5; ++d) {
        const float base = half ? rv[d] * LOG2E : rv[d];
        bh[d] = bf16rn(base);
        bl[d] = bf16rn(base - bf16tof(bh[d]));
    }
    const unsigned short hh  = bf16rn(h);
    const unsigned short hl  = bf16rn(h - bf16tof(hh));
    const unsigned short one = 0x3F80;

    unsigned short outv[8];
#pragma unroll
    for (int t = 0; t < 8; ++t) {
        const int k = q * 8 + t;
        unsigned short v = 0;
        if (!half) {
            if      (k < 5)   v = bh[k];
            else if (k < 10)  v = bh[k - 5];
            else if (k < 15)  v = bl[k - 10];
            else if (k == 15) v = hh;
            else if (k == 16) v = hl;
            else if (k <= 18) v = one;
        } else {
            if      (k < 5)   v = bh[k];
            else if (k < 10)  v = bl[k - 5];
            else if (k < 15)  v = bh[k - 10];
            else if (k <= 16) v = one;
            else if (k == 17) v = hh;
            else if (k == 18) v = hl;
        }
        outv[t] = v;
    }
    unsigned short* dst = (half ? packB : packA) + ((size_t)tile * 64 + lane) * 8;
    *(uint4*)dst = *(uint4*)outv;
}

// ---------------------------------------------------------------------------
// prep 2: pack U into PV A-fragments (bf16), utPack[jtile32][ct][lane][8].
__global__ __launch_bounds__(256) void prep_pack_ut(
    const float* __restrict__ U, unsigned short* __restrict__ utPack)
{
    __shared__ unsigned short tile[64 * 80];          // [c][jloc], stride 80
    const int t  = threadIdx.x;
    const int j0 = blockIdx.x * 64;
    const int c  = t & 63;
    const int jb = t >> 6;
#pragma unroll
    for (int k = 0; k < 16; ++k) {
        const int jr = jb + k * 4;
        tile[c * 80 + jr] = bf16rn(U[(size_t)(j0 + jr) * C_CH + c]);  // coalesced by c
    }
    __syncthreads();
#pragma unroll
    for (int rep = 0; rep < 2; ++rep) {
        const int id   = rep * 256 + t;               // 512 frag-lanes
        const int lane = id & 63;
        const int ct   = (id >> 6) & 3;
        const int kt   = id >> 8;                     // 0..1
        const int m    = lane & 15;
        const int q    = lane >> 4;
        const int cc   = ct * 16 + m;
        const int jloc = kt * 32 + q * 8;
        const uint4 frag = *(const uint4*)&tile[cc * 80 + jloc];
        const int jtile  = blockIdx.x * 2 + kt;
        *(uint4*)&utPack[(((size_t)jtile * 4 + ct) * 64 + lane) * 8] = frag;
    }
}

// ---------------------------------------------------------------------------
// main: barrier-free K-loop. grid = IBLOCKS*JSPLIT blocks, 256 threads.
// wave owns 4 i-tiles (64 i); block covers 256 i; j-range 2048 per block.
// uf/ga fragments read straight from L2 (utPack+packA fully L2-resident).
// Scores: 2 G-MFMAs -> exp2 -> per-(wave,s) 1KB LDS round-trip -> 4 PV-MFMAs.
__global__ __launch_bounds__(256, 2) void lsh_main(
    const float* __restrict__ U,
    const unsigned short* __restrict__ packA,
    const unsigned short* __restrict__ packB,
    const unsigned short* __restrict__ utPack,
    float* __restrict__ part,
    float* __restrict__ out,
    int use_part)
{
    __shared__ __align__(16) unsigned short sLds[16 * 512];   // 16 KB: [wave][s][512]

    const int t    = threadIdx.x;
    const int lane = t & 63;
    const int wave = t >> 6;
    const int q    = lane >> 4;
    const int m    = lane & 15;

    const int ib = blockIdx.x >> 3;
    const int js = blockIdx.x & 7;

    bf16x8 bfrag[4];
#pragma unroll
    for (int s = 0; s < 4; ++s) {
        const int itile = ib * 16 + wave * 4 + s;
        bfrag[s] = *(const bf16x8*)(packB + ((size_t)itile * 64 + lane) * 8);
    }

    f32x4 acc[4][4];
#pragma unroll
    for (int s = 0; s < 4; ++s)
#pragma unroll
        for (int ct = 0; ct < 4; ++ct) acc[s][ct] = (f32x4){0.f, 0.f, 0.f, 0.f};

    unsigned short* sBase = sLds + wave * 2048;       // 4 x 512 elems
    const int sWr0 = (q >> 1) * 128 + m * 8 + (q & 1) * 4;

    for (int chunk = 0; chunk < CHUNKS; ++chunk) {
#pragma unroll
        for (int kt = 0; kt < 4; ++kt) {
            const int jt32 = js * 64 + chunk * 4 + kt;
            const int jt16 = jt32 * 2;
            const bf16x8 ga0 = *(const bf16x8*)(packA + ((size_t)jt16 * 64 + lane) * 8);
            const bf16x8 ga1 = *(const bf16x8*)(packA + ((size_t)(jt16 + 1) * 64 + lane) * 8);
            bf16x8 uf[4];
#pragma unroll
            for (int ct = 0; ct < 4; ++ct)
                uf[ct] = *(const bf16x8*)(utPack + (((size_t)jt32 * 4 + ct) * 64 + lane) * 8);

            const f32x4 z = (f32x4){0.f, 0.f, 0.f, 0.f};
            f32x4 g0[4], g1[4];
#pragma unroll
            for (int s = 0; s < 4; ++s) {
                g0[s] = __builtin_amdgcn_mfma_f32_16x16x32_bf16(ga0, bfrag[s], z, 0, 0, 0);
                g1[s] = __builtin_amdgcn_mfma_f32_16x16x32_bf16(ga1, bfrag[s], z, 0, 0, 0);
            }
            // exp2 + pack + write all 4 s-tiles (independent 1KB buffers)
#pragma unroll
            for (int s = 0; s < 4; ++s) {
                float e0[4], e1[4];
#pragma unroll
                for (int r2 = 0; r2 < 4; ++r2) {
                    e0[r2] = fast_exp2(g0[s][r2]);
                    e1[r2] = fast_exp2(g1[s][r2]);
                }
                uint2 w0 = { pack2bf16(e0[0], e0[1]), pack2bf16(e0[2], e0[3]) };
                uint2 w1 = { pack2bf16(e1[0], e1[1]), pack2bf16(e1[2], e1[3]) };
                unsigned short* sb = sBase + s * 512;
                *(uint2*)&sb[sWr0]       = w0;        // j 0..15 rows
                *(uint2*)&sb[sWr0 + 256] = w1;        // j 16..31 rows
            }
            // read back as lane-sequential B-frags; same-wave DS is in-order
#pragma unroll
            for (int s = 0; s < 4; ++s) {
                const bf16x8 sf = *(const bf16x8*)&sBase[s * 512 + lane * 8];
#pragma unroll
                for (int ct = 0; ct < 4; ++ct)
                    acc[s][ct] = __builtin_amdgcn_mfma_f32_16x16x32_bf16(
                        uf[ct], sf, acc[s][ct], 0, 0, 0);
            }
        }
    }

    if (use_part) {
        // thread-linear coalesced partial store: part[js][ib][fidx][t]
        float* dst = part + (((size_t)js * IBLOCKS + ib) << 14) + t;
#pragma unroll
        for (int s = 0; s < 4; ++s)
#pragma unroll
            for (int ct = 0; ct < 4; ++ct)
#pragma unroll
                for (int r2 = 0; r2 < 4; ++r2) {
                    const int fidx = s * 16 + ct * 4 + r2;
                    dst[(size_t)fidx << 8] = acc[s][ct][r2];
                }
    } else {
#pragma unroll
        for (int s = 0; s < 4; ++s) {
            const int i_glob = (ib * 16 + wave * 4 + s) * 16 + m;
#pragma unroll
            for (int ct = 0; ct < 4; ++ct)
#pragma unroll
                for (int r2 = 0; r2 < 4; ++r2) {
                    const int c = ct * 16 + q * 4 + r2;
                    float val = acc[s][ct][r2];
                    if (js == 0) val -= U[(size_t)i_glob * C_CH + c];
                    atomicAdd(&out[(size_t)i_glob * C_CH + c], val);
                }
        }
    }
}

// ---------------------------------------------------------------------------
// reduce: out = sum_js part[js] - U, decoding the swizzled partial layout.
__global__ __launch_bounds__(256) void reduce_part(
    const float* __restrict__ part, const float* __restrict__ U,
    float* __restrict__ out)
{
    const int x = blockIdx.x * 256 + threadIdx.x;     // [0, 1<<20)
    float s = 0.f;
#pragma unroll
    for (int js = 0; js < JSPLIT; ++js)
        s += part[((size_t)js << 20) + x];

    const int ib   = x >> 14;
    const int fidx = (x >> 8) & 63;
    const int t    = x & 255;
    const int wave = t >> 6;
    const int lane = t & 63;
    const int m    = lane & 15;
    const int q    = lane >> 4;
    const int si   = fidx >> 4;
    const int ct   = (fidx >> 2) & 3;
    const int r2   = fidx & 3;
    const int i    = ib * 256 + (wave * 4 + si) * 16 + m;
    const int c    = ct * 16 + q * 4 + r2;
    const size_t o = (size_t)i * C_CH + c;
    out[o] = s - U[o];
}

extern "C" void kernel_launch(void* const* d_in, const int* in_sizes, int n_in,
                              void* d_out, int out_size, void* d_ws, size_t ws_size,
                              hipStream_t stream) {
    const float* U   = (const float*)d_in[0];
    const float* ref = (const float*)d_in[1];
    float* out = (float*)d_out;

    // ws: utPack 2 MB | packA 1 MB | packB 1 MB | partials 32 MB
    unsigned short* utPack = (unsigned short*)d_ws;
    unsigned short* packA  = (unsigned short*)((char*)d_ws + (size_t)2 * 1024 * 1024);
    unsigned short* packB  = (unsigned short*)((char*)d_ws + (size_t)3 * 1024 * 1024);
    float*          part   = (float*)((char*)d_ws + (size_t)4 * 1024 * 1024);

    const size_t need = (size_t)(4 + 4 * JSPLIT) * 1024 * 1024;
    const int use_part = (ws_size >= need) ? 1 : 0;

    if (!use_part)
        hipMemsetAsync(d_out, 0, (size_t)out_size * sizeof(float), stream);

    prep_pack_ref<<<512, 256, 0, stream>>>(ref, packA, packB);
    prep_pack_ut<<<N_PTS / 64, 256, 0, stream>>>(U, utPack);
    lsh_main<<<IBLOCKS * JSPLIT, 256, 0, stream>>>(U, packA, packB, utPack,
                                                   part, out, use_part);
    if (use_part)
        reduce_part<<<(1 << 20) / 256, 256, 0, stream>>>(part, U, out);
}

// Round 4
// 128.602 us; speedup vs baseline: 3.3865x; 1.1961x over previous
//
#include <hip/hip_runtime.h>
#include <hip/hip_bf16.h>
#include <stdint.h>

#define N_PTS 16384
#define C_CH  64
#define D_REF 5
#define LOG2E 1.44269504088896340736f
#define JSPLIT 8          // j-splits; partials reduced by second kernel
#define IBLOCKS 128       // blocks along i; 128 i per block (s=2 per wave)
#define CHUNKS 16         // per block: 2048 j = 16 chunks x 128 j

typedef __attribute__((ext_vector_type(8))) short bf16x8;
typedef __attribute__((ext_vector_type(4))) float f32x4;

__device__ __forceinline__ unsigned short bf16rn(float v) {
    unsigned u = __builtin_bit_cast(unsigned, v) + 0x8000u;   // round-half-up
    return (unsigned short)(u >> 16);
}
__device__ __forceinline__ float bf16tof(unsigned short h) {
    unsigned u = ((unsigned)h) << 16;
    return __builtin_bit_cast(float, u);
}
__device__ __forceinline__ unsigned pack2bf16(float lo, float hi) {
    unsigned a = __builtin_bit_cast(unsigned, lo) + 0x8000u;
    unsigned b = __builtin_bit_cast(unsigned, hi) + 0x8000u;
    return __builtin_amdgcn_perm(b, a, 0x07060302u);
}
__device__ __forceinline__ float fast_exp2(float x) {
#if __has_builtin(__builtin_amdgcn_exp2f)
    return __builtin_amdgcn_exp2f(x);
#else
    return exp2f(x);
#endif
}

// async global->LDS, 16B per lane; LDS dest = wave-uniform base + lane*16
__device__ __forceinline__ void dma16(const unsigned short* g, unsigned short* l) {
#if __has_builtin(__builtin_amdgcn_global_load_lds)
    __builtin_amdgcn_global_load_lds(
        (const __attribute__((address_space(1))) unsigned int*)g,
        (__attribute__((address_space(3))) unsigned int*)l, 16, 0, 0);
#else
    const int lane = threadIdx.x & 63;
    *(uint4*)(l + lane * 8) = *(const uint4*)(g);
#endif
}

// ---------------------------------------------------------------------------
// merged prep: blocks [0,512) pack ref into G-MFMA A/B fragment buffers,
// blocks [512,768) pack U into PV A-fragments.
//   G = sum_k A_k B_k = log2e*(ri.rj) + hi + hj  via hi/lo bf16 splits
//   (verified R2/R3, absmax 0.5).
__global__ __launch_bounds__(256) void prep_all(
    const float* __restrict__ U, const float* __restrict__ ref,
    unsigned short* __restrict__ packA, unsigned short* __restrict__ packB,
    unsigned short* __restrict__ utPack)
{
    __shared__ unsigned short tile[64 * 80];
    const int bid = blockIdx.x;
    const int t   = threadIdx.x;

    if (bid < 512) {
        const int gid  = bid * 256 + t;                // 131072 total
        const int half = gid >> 16;                    // 0 = A(j), 1 = B(i)
        const int id   = gid & 0xFFFF;
        const int tile16 = id >> 6;
        const int lane = id & 63;
        const int q    = lane >> 4;
        const int m    = lane & 15;
        const int p    = tile16 * 16 + m;

        const float* r = ref + (size_t)p * D_REF;
        float rv[5];
        float sq = 0.f;
#pragma unroll
        for (int d = 0; d < 5; ++d) { rv[d] = r[d]; sq += rv[d] * rv[d]; }
        const float h = -0.5f * LOG2E * sq;

        unsigned short bh[5], bl[5];
#pragma unroll
        for (int d = 0; d < 5; ++d) {
            const float base = half ? rv[d] * LOG2E : rv[d];
            bh[d] = bf16rn(base);
            bl[d] = bf16rn(base - bf16tof(bh[d]));
        }
        const unsigned short hh  = bf16rn(h);
        const unsigned short hl  = bf16rn(h - bf16tof(hh));
        const unsigned short one = 0x3F80;

        unsigned short outv[8];
#pragma unroll
        for (int tt = 0; tt < 8; ++tt) {
            const int k = q * 8 + tt;
            unsigned short v = 0;
            if (!half) {
                if      (k < 5)   v = bh[k];
                else if (k < 10)  v = bh[k - 5];
                else if (k < 15)  v = bl[k - 10];
                else if (k == 15) v = hh;
                else if (k == 16) v = hl;
                else if (k <= 18) v = one;
            } else {
                if      (k < 5)   v = bh[k];
                else if (k < 10)  v = bl[k - 5];
                else if (k < 15)  v = bh[k - 10];
                else if (k <= 16) v = one;
                else if (k == 17) v = hh;
                else if (k == 18) v = hl;
            }
            outv[tt] = v;
        }
        unsigned short* dst = (half ? packB : packA) + ((size_t)tile16 * 64 + lane) * 8;
        *(uint4*)dst = *(uint4*)outv;
    } else {
        const int b  = bid - 512;
        const int j0 = b * 64;
        const int c  = t & 63;
        const int jb = t >> 6;
#pragma unroll
        for (int k = 0; k < 16; ++k) {
            const int jr = jb + k * 4;
            tile[c * 80 + jr] = bf16rn(U[(size_t)(j0 + jr) * C_CH + c]);  // coalesced by c
        }
        __syncthreads();
#pragma unroll
        for (int rep = 0; rep < 2; ++rep) {
            const int id   = rep * 256 + t;            // 512 frag-lanes
            const int lane = id & 63;
            const int ct   = (id >> 6) & 3;
            const int kt   = id >> 8;                  // 0..1
            const int m    = lane & 15;
            const int q    = lane >> 4;
            const int cc   = ct * 16 + m;
            const int jloc = kt * 32 + q * 8;
            const uint4 frag = *(const uint4*)&tile[cc * 80 + jloc];
            const int jtile  = b * 2 + kt;
            *(uint4*)&utPack[(((size_t)jtile * 4 + ct) * 64 + lane) * 8] = frag;
        }
    }
}

// ---------------------------------------------------------------------------
// main: grid = IBLOCKS*JSPLIT = 1024 blocks x 256 thr -> 4 blocks/CU.
// Per chunk (128 j): DMA-stage utPack (16KB) + packA (8KB) into LDS, then
// 4 kt-steps: G-MFMA scores -> exp2 -> per-(wave,s) 1KB LDS round-trip ->
// PV-MFMA. Epilogue stores partials in natural (i,c) f32x4 order.
// LDS map (shorts): [0,8192) stage utPack | [8192,12288) stage packA |
//                   [12288,16384) score buffers (4 waves x 2 s x 512)
__global__ __launch_bounds__(256, 4) void lsh_main(
    const float* __restrict__ U,
    const unsigned short* __restrict__ packA,
    const unsigned short* __restrict__ packB,
    const unsigned short* __restrict__ utPack,
    float* __restrict__ part,
    float* __restrict__ out,
    int use_part)
{
    __shared__ __align__(16) unsigned short sh[16384];   // 32 KB

    const int t    = threadIdx.x;
    const int lane = t & 63;
    const int wave = t >> 6;
    const int q    = lane >> 4;
    const int m    = lane & 15;

    const int ib = blockIdx.x >> 3;     // 0..127
    const int js = blockIdx.x & 7;

    bf16x8 bfrag[2];
#pragma unroll
    for (int s = 0; s < 2; ++s) {
        const int itile = ib * 8 + wave * 2 + s;
        bfrag[s] = *(const bf16x8*)(packB + ((size_t)itile * 64 + lane) * 8);
    }

    f32x4 acc[2][4];
#pragma unroll
    for (int s = 0; s < 2; ++s)
#pragma unroll
        for (int ct = 0; ct < 4; ++ct) acc[s][ct] = (f32x4){0.f, 0.f, 0.f, 0.f};

    unsigned short* sW = sh + 12288 + wave * 1024;
    const int sWr0 = (q >> 1) * 128 + m * 8 + (q & 1) * 4;

    for (int chunk = 0; chunk < CHUNKS; ++chunk) {
        const unsigned short* srcU = utPack + (size_t)(js * 64 + chunk * 4) * 2048;
        const unsigned short* srcA = packA  + (size_t)(js * 128 + chunk * 8) * 512;
        __syncthreads();                               // prior chunk's reads done
#pragma unroll
        for (int r = 0; r < 4; ++r)
            dma16(srcU + r * 2048 + wave * 512 + lane * 8, sh + r * 2048 + wave * 512);
#pragma unroll
        for (int r = 0; r < 2; ++r)
            dma16(srcA + r * 2048 + wave * 512 + lane * 8, sh + 8192 + r * 2048 + wave * 512);
        __syncthreads();                               // drains vmcnt -> LDS valid

#pragma unroll
        for (int kt = 0; kt < 4; ++kt) {
            const bf16x8 ga0 = *(const bf16x8*)(sh + 8192 + (kt * 2 + 0) * 512 + lane * 8);
            const bf16x8 ga1 = *(const bf16x8*)(sh + 8192 + (kt * 2 + 1) * 512 + lane * 8);
            bf16x8 uf[4];
#pragma unroll
            for (int ct = 0; ct < 4; ++ct)
                uf[ct] = *(const bf16x8*)(sh + kt * 2048 + ct * 512 + lane * 8);

            const f32x4 z = (f32x4){0.f, 0.f, 0.f, 0.f};
            f32x4 g0[2], g1[2];
#pragma unroll
            for (int s = 0; s < 2; ++s) {
                g0[s] = __builtin_amdgcn_mfma_f32_16x16x32_bf16(ga0, bfrag[s], z, 0, 0, 0);
                g1[s] = __builtin_amdgcn_mfma_f32_16x16x32_bf16(ga1, bfrag[s], z, 0, 0, 0);
            }
#pragma unroll
            for (int s = 0; s < 2; ++s) {
                float e0[4], e1[4];
#pragma unroll
                for (int r2 = 0; r2 < 4; ++r2) {
                    e0[r2] = fast_exp2(g0[s][r2]);
                    e1[r2] = fast_exp2(g1[s][r2]);
                }
                uint2 w0 = { pack2bf16(e0[0], e0[1]), pack2bf16(e0[2], e0[3]) };
                uint2 w1 = { pack2bf16(e1[0], e1[1]), pack2bf16(e1[2], e1[3]) };
                unsigned short* sb = sW + s * 512;
                *(uint2*)&sb[sWr0]       = w0;         // j 0..15 rows
                *(uint2*)&sb[sWr0 + 256] = w1;         // j 16..31 rows
            }
            // same-wave DS in-order: read back as lane-sequential B-frags
#pragma unroll
            for (int s = 0; s < 2; ++s) {
                const bf16x8 sf = *(const bf16x8*)&sW[s * 512 + lane * 8];
#pragma unroll
                for (int ct = 0; ct < 4; ++ct)
                    acc[s][ct] = __builtin_amdgcn_mfma_f32_16x16x32_bf16(
                        uf[ct], sf, acc[s][ct], 0, 0, 0);
            }
        }
    }

    if (use_part) {
        // natural (i,c) order: part[js][ib*128 + i_loc][c] -> reduce is linear
        float* dst = part + ((size_t)js * IBLOCKS + ib) * (128 * C_CH);
#pragma unroll
        for (int s = 0; s < 2; ++s) {
            const int i_loc = (wave * 2 + s) * 16 + m;
#pragma unroll
            for (int ct = 0; ct < 4; ++ct)
                *(f32x4*)(dst + i_loc * C_CH + ct * 16 + q * 4) = acc[s][ct];
        }
    } else {
#pragma unroll
        for (int s = 0; s < 2; ++s) {
            const int i_glob = ib * 128 + (wave * 2 + s) * 16 + m;
#pragma unroll
            for (int ct = 0; ct < 4; ++ct)
#pragma unroll
                for (int r2 = 0; r2 < 4; ++r2) {
                    const int c = ct * 16 + q * 4 + r2;
                    float val = acc[s][ct][r2];
                    if (js == 0) val -= U[(size_t)i_glob * C_CH + c];
                    atomicAdd(&out[(size_t)i_glob * C_CH + c], val);
                }
        }
    }
}

// ---------------------------------------------------------------------------
// reduce: out = sum_js part[js] - U; all streams fully coalesced float4.
__global__ __launch_bounds__(256) void reduce_part(
    const f32x4* __restrict__ part, const f32x4* __restrict__ U,
    f32x4* __restrict__ out)
{
    const int x = blockIdx.x * 256 + threadIdx.x;      // [0, 1<<18)
    f32x4 s = part[x];
#pragma unroll
    for (int js = 1; js < JSPLIT; ++js)
        s += part[((size_t)js << 18) + x];
    out[x] = s - U[x];
}

extern "C" void kernel_launch(void* const* d_in, const int* in_sizes, int n_in,
                              void* d_out, int out_size, void* d_ws, size_t ws_size,
                              hipStream_t stream) {
    const float* U   = (const float*)d_in[0];
    const float* ref = (const float*)d_in[1];
    float* out = (float*)d_out;

    // ws: utPack 2 MB | packA 1 MB | packB 1 MB | partials 32 MB
    unsigned short* utPack = (unsigned short*)d_ws;
    unsigned short* packA  = (unsigned short*)((char*)d_ws + (size_t)2 * 1024 * 1024);
    unsigned short* packB  = (unsigned short*)((char*)d_ws + (size_t)3 * 1024 * 1024);
    float*          part   = (float*)((char*)d_ws + (size_t)4 * 1024 * 1024);

    const size_t need = (size_t)(4 + 4 * JSPLIT) * 1024 * 1024;
    const int use_part = (ws_size >= need) ? 1 : 0;

    if (!use_part)
        hipMemsetAsync(d_out, 0, (size_t)out_size * sizeof(float), stream);

    prep_all<<<768, 256, 0, stream>>>(U, ref, packA, packB, utPack);
    lsh_main<<<IBLOCKS * JSPLIT, 256, 0, stream>>>(U, packA, packB, utPack,
                                                   part, out, use_part);
    if (use_part)
        reduce_part<<<1024, 256, 0, stream>>>((const f32x4*)part, (const f32x4*)U,
                                              (f32x4*)out);
}

// Round 5
// 126.505 us; speedup vs baseline: 3.4426x; 1.0166x over previous
//
#include <hip/hip_runtime.h>
#include <hip/hip_bf16.h>
#include <stdint.h>

#define N_PTS 16384
#define C_CH  64
#define D_REF 5
#define LOG2E 1.44269504088896340736f
#define IBLOCKS 64        // 256 i per block (4 waves x 4 i-tiles x 16)

typedef __attribute__((ext_vector_type(8))) short bf16x8;
typedef __attribute__((ext_vector_type(4))) float f32x4;

__device__ __forceinline__ unsigned short bf16rn(float v) {
    unsigned u = __builtin_bit_cast(unsigned, v) + 0x8000u;   // round-half-up
    return (unsigned short)(u >> 16);
}
__device__ __forceinline__ float bf16tof(unsigned short h) {
    unsigned u = ((unsigned)h) << 16;
    return __builtin_bit_cast(float, u);
}
__device__ __forceinline__ unsigned pack2bf16(float lo, float hi) {
    unsigned a = __builtin_bit_cast(unsigned, lo) + 0x8000u;
    unsigned b = __builtin_bit_cast(unsigned, hi) + 0x8000u;
    return __builtin_amdgcn_perm(b, a, 0x07060302u);
}
__device__ __forceinline__ float fast_exp2(float x) {
#if __has_builtin(__builtin_amdgcn_exp2f)
    return __builtin_amdgcn_exp2f(x);
#else
    return exp2f(x);
#endif
}

// async global->LDS, 16B per lane; LDS dest = wave-uniform base + lane*16
__device__ __forceinline__ void dma16(const unsigned short* g, unsigned short* l) {
#if __has_builtin(__builtin_amdgcn_global_load_lds)
    __builtin_amdgcn_global_load_lds(
        (const __attribute__((address_space(1))) unsigned int*)g,
        (__attribute__((address_space(3))) unsigned int*)l, 16, 0, 0);
#else
    const int lane = threadIdx.x & 63;
    *(uint4*)(l + lane * 8) = *(const uint4*)(g);
#endif
}

// ---------------------------------------------------------------------------
// merged prep: blocks [0,512) pack ref into G-MFMA A/B fragment buffers,
// blocks [512,768) pack U into PV A-fragments.
//   G = sum_k A_k B_k = log2e*(ri.rj) + hi + hj  via hi/lo bf16 splits.
// PV-DIRECT PERMUTATION: packA tile pair (g = jt16>>1 covers 32 j, h = jt16&1):
//   A-row w of tile h holds point j = g*32 + (w>>2)*8 + (w&3) + 4h.
// Then G-pair output regs {g0[0..3], g1[0..3]} on lane (q,m) are exactly
// S[j = q*8 + t][i = m], t=0..7 == the PV B-operand fragment. No LDS round-trip.
__global__ __launch_bounds__(256) void prep_all(
    const float* __restrict__ U, const float* __restrict__ ref,
    unsigned short* __restrict__ packA, unsigned short* __restrict__ packB,
    unsigned short* __restrict__ utPack)
{
    __shared__ unsigned short tile[64 * 80];
    const int bid = blockIdx.x;
    const int t   = threadIdx.x;

    if (bid < 512) {
        const int gid  = bid * 256 + t;                // 131072 total
        const int half = gid >> 16;                    // 0 = A(j), 1 = B(i)
        const int id   = gid & 0xFFFF;
        const int tile16 = id >> 6;
        const int lane = id & 63;
        const int q    = lane >> 4;
        const int m    = lane & 15;
        // A-side: permuted row->point map; B-side: natural
        const int p = half ? (tile16 * 16 + m)
                           : ((tile16 >> 1) * 32 + (m >> 2) * 8 + (m & 3) + (tile16 & 1) * 4);

        const float* r = ref + (size_t)p * D_REF;
        float rv[5];
        float sq = 0.f;
#pragma unroll
        for (int d = 0; d < 5; ++d) { rv[d] = r[d]; sq += rv[d] * rv[d]; }
        const float h = -0.5f * LOG2E * sq;

        unsigned short bh[5], bl[5];
#pragma unroll
        for (int d = 0; d < 5; ++d) {
            const float base = half ? rv[d] * LOG2E : rv[d];
            bh[d] = bf16rn(base);
            bl[d] = bf16rn(base - bf16tof(bh[d]));
        }
        const unsigned short hh  = bf16rn(h);
        const unsigned short hl  = bf16rn(h - bf16tof(hh));
        const unsigned short one = 0x3F80;

        unsigned short outv[8];
#pragma unroll
        for (int tt = 0; tt < 8; ++tt) {
            const int k = q * 8 + tt;
            unsigned short v = 0;
            if (!half) {
                if      (k < 5)   v = bh[k];
                else if (k < 10)  v = bh[k - 5];
                else if (k < 15)  v = bl[k - 10];
                else if (k == 15) v = hh;
                else if (k == 16) v = hl;
                else if (k <= 18) v = one;
            } else {
                if      (k < 5)   v = bh[k];
                else if (k < 10)  v = bl[k - 5];
                else if (k < 15)  v = bh[k - 10];
                else if (k <= 16) v = one;
                else if (k == 17) v = hh;
                else if (k == 18) v = hl;
            }
            outv[tt] = v;
        }
        unsigned short* dst = (half ? packB : packA) + ((size_t)tile16 * 64 + lane) * 8;
        *(uint4*)dst = *(uint4*)outv;
    } else {
        const int b  = bid - 512;
        const int j0 = b * 64;
        const int c  = t & 63;
        const int jb = t >> 6;
#pragma unroll
        for (int k = 0; k < 16; ++k) {
            const int jr = jb + k * 4;
            tile[c * 80 + jr] = bf16rn(U[(size_t)(j0 + jr) * C_CH + c]);  // coalesced by c
        }
        __syncthreads();
#pragma unroll
        for (int rep = 0; rep < 2; ++rep) {
            const int id   = rep * 256 + t;            // 512 frag-lanes
            const int lane = id & 63;
            const int ct   = (id >> 6) & 3;
            const int kt   = id >> 8;                  // 0..1
            const int m    = lane & 15;
            const int q    = lane >> 4;
            const int cc   = ct * 16 + m;
            const int jloc = kt * 32 + q * 8;
            const uint4 frag = *(const uint4*)&tile[cc * 80 + jloc];
            const int jtile  = b * 2 + kt;
            *(uint4*)&utPack[(((size_t)jtile * 4 + ct) * 64 + lane) * 8] = frag;
        }
    }
}

// ---------------------------------------------------------------------------
// main: grid = IBLOCKS*JS blocks x 256 thr. Wave owns 4 i-tiles (s=0..3).
// Per chunk (128 j): DMA-stage utPack (16KB) + packA (8KB), then 4 kt-steps:
//   G-MFMA pair (permuted A rows) -> exp2 -> pack = PV B-frag directly ->
//   4 PV-MFMAs per s. Zero score LDS traffic.
// LDS (shorts): [0,8192) utPack stage | [8192,12288) packA stage. 24 KB.
template<int JS>
__global__ __launch_bounds__(256, 4) void lsh_main(
    const float* __restrict__ U,
    const unsigned short* __restrict__ packA,
    const unsigned short* __restrict__ packB,
    const unsigned short* __restrict__ utPack,
    float* __restrict__ part,
    float* __restrict__ out,
    int use_part)
{
    constexpr int CHUNKS = (N_PTS / JS) / 128;
    __shared__ __align__(16) unsigned short sh[12288];   // 24 KB

    const int t    = threadIdx.x;
    const int lane = t & 63;
    const int wave = t >> 6;
    const int q    = lane >> 4;
    const int m    = lane & 15;

    const int ib = blockIdx.x / JS;     // 0..63
    const int js = blockIdx.x % JS;

    bf16x8 bfrag[4];
#pragma unroll
    for (int s = 0; s < 4; ++s) {
        const int itile = ib * 16 + wave * 4 + s;
        bfrag[s] = *(const bf16x8*)(packB + ((size_t)itile * 64 + lane) * 8);
    }

    f32x4 acc[4][4];
#pragma unroll
    for (int s = 0; s < 4; ++s)
#pragma unroll
        for (int ct = 0; ct < 4; ++ct) acc[s][ct] = (f32x4){0.f, 0.f, 0.f, 0.f};

    for (int chunk = 0; chunk < CHUNKS; ++chunk) {
        const unsigned short* srcU = utPack + (size_t)(js * CHUNKS + chunk) * 8192;
        const unsigned short* srcA = packA  + (size_t)(js * CHUNKS + chunk) * 4096;
        __syncthreads();                               // prior chunk's reads done
#pragma unroll
        for (int r = 0; r < 4; ++r)
            dma16(srcU + r * 2048 + wave * 512 + lane * 8, sh + r * 2048 + wave * 512);
#pragma unroll
        for (int r = 0; r < 2; ++r)
            dma16(srcA + r * 2048 + wave * 512 + lane * 8, sh + 8192 + r * 2048 + wave * 512);
        __syncthreads();                               // drains vmcnt -> LDS valid

#pragma unroll
        for (int kt = 0; kt < 4; ++kt) {
            const bf16x8 ga0 = *(const bf16x8*)(sh + 8192 + (kt * 2 + 0) * 512 + lane * 8);
            const bf16x8 ga1 = *(const bf16x8*)(sh + 8192 + (kt * 2 + 1) * 512 + lane * 8);

            const f32x4 z = (f32x4){0.f, 0.f, 0.f, 0.f};
            bf16x8 sfrag[4];
#pragma unroll
            for (int s = 0; s < 4; ++s) {
                const f32x4 g0 = __builtin_amdgcn_mfma_f32_16x16x32_bf16(ga0, bfrag[s], z, 0, 0, 0);
                const f32x4 g1 = __builtin_amdgcn_mfma_f32_16x16x32_bf16(ga1, bfrag[s], z, 0, 0, 0);
                union { unsigned u[4]; bf16x8 v; } sb;
                sb.u[0] = pack2bf16(fast_exp2(g0[0]), fast_exp2(g0[1]));
                sb.u[1] = pack2bf16(fast_exp2(g0[2]), fast_exp2(g0[3]));
                sb.u[2] = pack2bf16(fast_exp2(g1[0]), fast_exp2(g1[1]));
                sb.u[3] = pack2bf16(fast_exp2(g1[2]), fast_exp2(g1[3]));
                sfrag[s] = sb.v;                       // == PV B-frag for 32 j
            }
#pragma unroll
            for (int ct = 0; ct < 4; ++ct) {
                const bf16x8 uf = *(const bf16x8*)(sh + kt * 2048 + ct * 512 + lane * 8);
#pragma unroll
                for (int s = 0; s < 4; ++s)
                    acc[s][ct] = __builtin_amdgcn_mfma_f32_16x16x32_bf16(
                        uf, sfrag[s], acc[s][ct], 0, 0, 0);
            }
        }
    }

    if (use_part) {
        // natural (i,c) order: part[js][ib*256 + i_loc][c] -> reduce is linear
        float* dst = part + ((size_t)js * IBLOCKS + ib) * (256 * C_CH);
#pragma unroll
        for (int s = 0; s < 4; ++s) {
            const int i_loc = (wave * 4 + s) * 16 + m;
#pragma unroll
            for (int ct = 0; ct < 4; ++ct)
                *(f32x4*)(dst + i_loc * C_CH + ct * 16 + q * 4) = acc[s][ct];
        }
    } else {
#pragma unroll
        for (int s = 0; s < 4; ++s) {
            const int i_glob = ib * 256 + (wave * 4 + s) * 16 + m;
#pragma unroll
            for (int ct = 0; ct < 4; ++ct)
#pragma unroll
                for (int r2 = 0; r2 < 4; ++r2) {
                    const int c = ct * 16 + q * 4 + r2;
                    float val = acc[s][ct][r2];
                    if (js == 0) val -= U[(size_t)i_glob * C_CH + c];
                    atomicAdd(&out[(size_t)i_glob * C_CH + c], val);
                }
        }
    }
}

// ---------------------------------------------------------------------------
// reduce: out = sum_js part[js] - U; all streams fully coalesced float4.
template<int JS>
__global__ __launch_bounds__(256) void reduce_part(
    const f32x4* __restrict__ part, const f32x4* __restrict__ U,
    f32x4* __restrict__ out)
{
    const int x = blockIdx.x * 256 + threadIdx.x;      // [0, 1<<18)
    f32x4 s = part[x];
#pragma unroll
    for (int js = 1; js < JS; ++js)
        s += part[((size_t)js << 18) + x];
    out[x] = s - U[x];
}

extern "C" void kernel_launch(void* const* d_in, const int* in_sizes, int n_in,
                              void* d_out, int out_size, void* d_ws, size_t ws_size,
                              hipStream_t stream) {
    const float* U   = (const float*)d_in[0];
    const float* ref = (const float*)d_in[1];
    float* out = (float*)d_out;

    // ws: utPack 2 MB | packA 1 MB | packB 1 MB | partials 4 MB * JS
    unsigned short* utPack = (unsigned short*)d_ws;
    unsigned short* packA  = (unsigned short*)((char*)d_ws + (size_t)2 * 1024 * 1024);
    unsigned short* packB  = (unsigned short*)((char*)d_ws + (size_t)3 * 1024 * 1024);
    float*          part   = (float*)((char*)d_ws + (size_t)4 * 1024 * 1024);

    const size_t MB = 1024 * 1024;
    prep_all<<<768, 256, 0, stream>>>(U, ref, packA, packB, utPack);

    if (ws_size >= (4 + 4 * 16) * MB) {
        lsh_main<16><<<IBLOCKS * 16, 256, 0, stream>>>(U, packA, packB, utPack,
                                                       part, out, 1);
        reduce_part<16><<<1024, 256, 0, stream>>>((const f32x4*)part,
                                                  (const f32x4*)U, (f32x4*)out);
    } else if (ws_size >= (4 + 4 * 8) * MB) {
        lsh_main<8><<<IBLOCKS * 8, 256, 0, stream>>>(U, packA, packB, utPack,
                                                     part, out, 1);
        reduce_part<8><<<1024, 256, 0, stream>>>((const f32x4*)part,
                                                 (const f32x4*)U, (f32x4*)out);
    } else {
        hipMemsetAsync(d_out, 0, (size_t)out_size * sizeof(float), stream);
        lsh_main<8><<<IBLOCKS * 8, 256, 0, stream>>>(U, packA, packB, utPack,
                                                     part, out, 0);
    }
}